// Round 1
// 310.088 us; speedup vs baseline: 1.2001x; 1.2001x over previous
//
#include <hip/hip_runtime.h>
#include <hip/hip_bf16.h>

typedef __attribute__((ext_vector_type(8))) short short8;
typedef __attribute__((ext_vector_type(4))) short short4_;
typedef __attribute__((ext_vector_type(4))) float float4_;

#define CH 64
#define HH 256
#define WW 256
#define HW (HH*WW)
#define CHW (CH*HW)

#define TW 16
#define TH 8
#define XPW 20
#define XPH 12
#define NXP 240        // x/qkv halo set (halo 2)
#define OPW 18
#define OPH 10
#define NOP 180        // out1 set (halo 1)

#define XLS 72         // x LDS row stride (shorts) -> 144 B, 16B aligned
#define KQS 20         // k/q chunk row stride (shorts): 10 dwords -> quads hit
                       // disjoint bank octets (8*quad + n16/2): conflict-free stores
#define O1S 72         // out1 row stride (shorts), 144 B = 9*16 -> b128-alignable
#define TSF 33         // tbuf row stride (floats): reads spread all 32 banks

#define KQ_SZ   (NXP*KQS)            // 4800 shorts
#define O1_OFF  KQ_SZ                // o1b shares qbuf region (time-disjoint)
#define SMEM_SHORTS (O1_OFF + NOP*O1S)   // 4800 + 12960 = 17760 -> 35520 B
                                         // (xls needs 17280 <= 17760: ok)

// ws layout: wsq bf16 [0,24576) ; wsm bf16 [24576, 98304)
#define WSQ_SHORTS 12288
#define WSM_SHORTS 36864

__device__ __forceinline__ float b2f(unsigned short u) {
    return __uint_as_float(((unsigned)u) << 16);
}
__device__ __forceinline__ short f2bs(float f) {
    __hip_bfloat16 h = __float2bfloat16(f);
    short s; __builtin_memcpy(&s, &h, 2); return s;
}

// ---- prep: pack wqkv/wmlp to bf16 in exact B-fragment order -----------------
__global__ void prep_pack(const float* __restrict__ wqkv,
                          const float* __restrict__ wmlp,
                          short* __restrict__ wsq, short* __restrict__ wsm) {
    int idx = blockIdx.x * blockDim.x + threadIdx.x;
    int stride = gridDim.x * blockDim.x;
    for (int e = idx; e < WSQ_SHORTS; e += stride) {
        int j = e & 7, lane = (e >> 3) & 63;
        int ks = (e >> 9) & 1, q16 = (e >> 10) & 3, sec = e >> 12;
        int row = sec*64 + q16*16 + (lane & 15);
        int kk  = ks*32 + (lane >> 4)*8 + j;
        wsq[e] = f2bs(wqkv[(size_t)row*64 + kk]);
    }
    for (int e = idx; e < WSM_SHORTS; e += stride) {
        int j = e & 7, lane = (e >> 3) & 63;
        int rest = e >> 9;            // 0..71
        int nt = rest / 18, ks = rest % 18;
        int o   = nt*16 + (lane & 15);
        int cin = (ks & 1)*32 + (lane >> 4)*8 + j;
        int tap = ks >> 1;
        wsm[e] = f2bs(wmlp[(size_t)o*576 + cin*9 + tap]);
    }
}

// ---- fused kernel -----------------------------------------------------------
// LDS 35520 B -> 4 blocks/CU (vs 43200 B / 3 blocks before). qbuf and o1b
// share one region: qbuf is dead after the QK rounds, o1b first written in
// the V rounds (barrier-separated).
__global__ __launch_bounds__(256, 4) void fused_mfma(
    const float* __restrict__ x, const short* __restrict__ wsq,
    const float* __restrict__ bqkv, const short* __restrict__ wsm,
    float* __restrict__ out)
{
    __shared__ __align__(16) short smem[SMEM_SHORTS];
    short* xls  = smem;                              // [240][72] (phase X only)
    short* kbuf = smem;                              // [240][20]
    short* qbuf = smem + O1_OFF;                     // [240][20] (QK rounds)
    short* o1b  = smem + O1_OFF;                     // [180][72] (V rounds/conv)
    float* tbuf = (float*)smem;                      // [128][33] (conv epilogue)

    const int t    = threadIdx.x;
    const int w    = t >> 6;
    const int lane = t & 63;
    const int n16  = lane & 15;
    const int quad = lane >> 4;

    const int b   = blockIdx.z;
    const int gy0 = blockIdx.y * TH;
    const int gx0 = blockIdx.x * TW;
    const float* xb = x + (size_t)b * CHW;

    // NOTE: all 4 waves process exactly 4 M-tiles (16th tile is a clamped
    // dummy) so that every register-array index is compile-time static.
    // Dynamic-bound loops over register arrays (round 5/6) caused scratch
    // spills: WRITE_SIZE 188MB vs 67MB ideal.

    // ---- phase X: stage x halo tile into LDS bf16, coalesced float4 loads
    for (int slot = t; slot < 64*12*6; slot += 256) {
        int s6 = slot % 6, y = (slot / 6) % 12, c = slot / 72;
        int gy = gy0 - 2 + y;
        int gxb = gx0 - 4 + s6*4;
        float v[4];
        bool gyok = (unsigned)gy < HH;
        if (gyok && gxb >= 0 && gxb + 3 < WW) {
            float4_ f4 = *(const float4_*)(xb + (size_t)c*HW + gy*WW + gxb);
            v[0]=f4[0]; v[1]=f4[1]; v[2]=f4[2]; v[3]=f4[3];
        } else {
            #pragma unroll
            for (int i = 0; i < 4; ++i) {
                int gx = gxb + i;
                v[i] = (gyok && (unsigned)gx < WW) ? xb[(size_t)c*HW + gy*WW + gx] : 0.f;
            }
        }
        #pragma unroll
        for (int i = 0; i < 4; ++i) {
            int pxc = s6*4 + i - 2;
            if ((unsigned)pxc < XPW)
                xls[(y*XPW + pxc)*XLS + c] = f2bs(v[i]);
        }
    }
    __syncthreads();

    // OOB bitmask: bit(i*4+r) -> halo pixel (w*4+i)*16 + quad*4 + r
    unsigned okbits = 0;
    #pragma unroll
    for (int i = 0; i < 4; ++i)
        #pragma unroll
        for (int r = 0; r < 4; ++r) {
            int p = (w*4 + i)*16 + quad*4 + r;
            if (p < NXP) {
                int gy = gy0 - 2 + p / XPW, gx = gx0 - 2 + p % XPW;
                if (((unsigned)gy < HH) && ((unsigned)gx < WW))
                    okbits |= 1u << (i*4 + r);
            }
        }

    // ---- A-frags (from LDS, static-indexed) + residual capture
    short8 afr[4][2];
    #pragma unroll
    for (int i = 0; i < 4; ++i) {
        int p = (w*4 + i)*16 + n16;
        int pr = (p < NXP) ? p : 0;        // clamped dummy for wave3/i3
        #pragma unroll
        for (int ks = 0; ks < 2; ++ks)
            afr[i][ks] = *(const short8*)&xls[pr*XLS + ks*32 + quad*8];
    }
    // per-thread attention pixel
    const int op_py = t / OPW, op_px = t % OPW;
    const int ogy = gy0 - 1 + op_py, ogx = gx0 - 1 + op_px;
    const bool oin = (t < NOP) && ((unsigned)ogy < HH) && ((unsigned)ogx < WW);
    const int xpix = (op_py + 1)*XPW + (op_px + 1);
    short8 resi[8];
    if (t < NOP) {
        #pragma unroll
        for (int g = 0; g < 8; ++g)
            resi[g] = *(const short8*)&xls[xpix*XLS + g*8];
    }
    __syncthreads();   // xls dead; k/q regions may now be written

    // gemm one 16-outch chunk of section sec (0=q,1=k,2=v) into dst
    auto gemm16 = [&](int sec, int q16, short* dst) {
        short8 b0 = *(const short8*)&wsq[(((sec*4 + q16)*2 + 0) << 9) + lane*8];
        short8 b1 = *(const short8*)&wsq[(((sec*4 + q16)*2 + 1) << 9) + lane*8];
        float bias = bqkv[sec*64 + q16*16 + n16];
        #pragma unroll
        for (int i = 0; i < 4; ++i) {
            float4_ c = {0.f, 0.f, 0.f, 0.f};
            c = __builtin_amdgcn_mfma_f32_16x16x32_bf16(afr[i][0], b0, c, 0, 0, 0);
            c = __builtin_amdgcn_mfma_f32_16x16x32_bf16(afr[i][1], b1, c, 0, 0, 0);
            #pragma unroll
            for (int r = 0; r < 4; ++r) {
                int p = (w*4 + i)*16 + quad*4 + r;
                bool ok = (okbits >> (i*4 + r)) & 1u;
                if (p < NXP)                        // guard dummy tile
                    dst[p*KQS + n16] = ok ? f2bs(c[r] + bias) : (short)0;
            }
        }
    };

    // ---- QK rounds (4 x 16 channels) + dot accumulation
    float dots[9];
    #pragma unroll
    for (int n = 0; n < 9; ++n) dots[n] = 0.f;

    #pragma unroll
    for (int q16 = 0; q16 < 4; ++q16) {
        gemm16(0, q16, qbuf);
        gemm16(1, q16, kbuf);
        __syncthreads();
        if (oin) {
            #pragma unroll
            for (int g = 0; g < 4; ++g) {
                short4_ q4 = *(const short4_*)&qbuf[xpix*KQS + g*4];
                float qv[4];
                #pragma unroll
                for (int j = 0; j < 4; ++j) qv[j] = b2f((unsigned short)q4[j]);
                #pragma unroll
                for (int n = 0; n < 9; ++n) {
                    int np = xpix + (n/3 - 1)*XPW + (n%3 - 1);
                    short4_ k4 = *(const short4_*)&kbuf[np*KQS + g*4];
                    #pragma unroll
                    for (int j = 0; j < 4; ++j) dots[n] += qv[j] * b2f((unsigned short)k4[j]);
                }
            }
        }
        __syncthreads();
    }

    // ---- softmax (registers)
    float attn[9];
    if (oin) {
        float mx = -1e30f;
        #pragma unroll
        for (int n = 0; n < 9; ++n) { dots[n] *= 0.125f; mx = fmaxf(mx, dots[n]); }
        float se = 0.f;
        #pragma unroll
        for (int n = 0; n < 9; ++n) { attn[n] = __expf(dots[n] - mx); se += attn[n]; }
        float inv = 1.f / se;
        #pragma unroll
        for (int n = 0; n < 9; ++n) attn[n] *= inv;
    }

    // ---- V rounds (4 x 16 channels): gemm v -> aggregate into o1b (bf16)
    // o1b writes are two ds_write_b128 per thread (16B-aligned rows, group
    // index (t+c)&7 is uniform -> conflict-free; the old 8x b32 stores were
    // 8-way conflicted: bank 4*(t&7)+g used only 8 banks).
    #pragma unroll
    for (int q16 = 0; q16 < 4; ++q16) {
        gemm16(2, q16, kbuf);
        __syncthreads();
        if (t < NOP) {
            short8 s0, s1;
            if (oin) {
                float o1[16];
                #pragma unroll
                for (int h = 0; h < 2; ++h) {
                    short8 rg = resi[q16*2 + h];
                    #pragma unroll
                    for (int j = 0; j < 8; ++j) o1[h*8 + j] = b2f((unsigned short)rg[j]);
                }
                #pragma unroll
                for (int n = 0; n < 9; ++n) {
                    float a = attn[n];
                    int np = xpix + (n/3 - 1)*XPW + (n%3 - 1);
                    #pragma unroll
                    for (int g = 0; g < 4; ++g) {
                        short4_ v4 = *(const short4_*)&kbuf[np*KQS + g*4];
                        #pragma unroll
                        for (int j = 0; j < 4; ++j) o1[g*4 + j] += a * b2f((unsigned short)v4[j]);
                    }
                }
                #pragma unroll
                for (int j = 0; j < 8; ++j) {
                    s0[j] = f2bs(o1[j]);
                    s1[j] = f2bs(o1[8 + j]);
                }
            } else {
                #pragma unroll
                for (int j = 0; j < 8; ++j) { s0[j] = 0; s1[j] = 0; }  // conv zero-pad
            }
            *(short8*)&o1b[t*O1S + q16*16]     = s0;
            *(short8*)&o1b[t*O1S + q16*16 + 8] = s1;
        }
        __syncthreads();
    }

    // ---- 3x3 conv 64->64 as one MFMA burst (K=576 tap-major), B from ws
    float4_ acc[4][2];
    #pragma unroll
    for (int nt = 0; nt < 4; ++nt) {
        acc[nt][0] = (float4_){0.f,0.f,0.f,0.f};
        acc[nt][1] = (float4_){0.f,0.f,0.f,0.f};
    }
    const int mtc0 = w*2, mtc1 = w*2 + 1;
    for (int ks = 0; ks < 18; ++ks) {
        int tap = ks >> 1;
        int dy = tap/3 - 1, dx = tap%3 - 1;
        int cin0 = (ks & 1)*32 + quad*8;
        int pixA = (mtc0 + 1 + dy)*OPW + (n16 + 1 + dx);
        int pixB = (mtc1 + 1 + dy)*OPW + (n16 + 1 + dx);
        short8 a0 = *(const short8*)&o1b[pixA*O1S + cin0];
        short8 a1 = *(const short8*)&o1b[pixB*O1S + cin0];
        #pragma unroll
        for (int nt = 0; nt < 4; ++nt) {
            short8 bb = *(const short8*)&wsm[((nt*18 + ks) << 9) + lane*8];
            acc[nt][0] = __builtin_amdgcn_mfma_f32_16x16x32_bf16(a0, bb, acc[nt][0], 0, 0, 0);
            acc[nt][1] = __builtin_amdgcn_mfma_f32_16x16x32_bf16(a1, bb, acc[nt][1], 0, 0, 0);
        }
    }
    __syncthreads();   // o1b overlaps tbuf region now: all conv reads must land

    // ---- epilogue: two 32-channel halves through tbuf, coalesced stores
    #pragma unroll
    for (int half = 0; half < 2; ++half) {
        #pragma unroll
        for (int ntl = 0; ntl < 2; ++ntl) {
            int nt = half*2 + ntl;
            #pragma unroll
            for (int r = 0; r < 4; ++r) {
                tbuf[(mtc0*16 + quad*4 + r)*TSF + ntl*16 + n16] = fmaxf(acc[nt][0][r], 0.f);
                tbuf[(mtc1*16 + quad*4 + r)*TSF + ntl*16 + n16] = fmaxf(acc[nt][1][r], 0.f);
            }
        }
        __syncthreads();
        {
            int pl = t & 127, oh = t >> 7;
            int ty_ = pl >> 4, tx_ = pl & 15;
            float* op = out + (size_t)b*CHW + (size_t)(half*32 + oh*16)*HW
                        + (size_t)(gy0 + ty_)*WW + (gx0 + tx_);
            #pragma unroll
            for (int ii = 0; ii < 16; ++ii)
                op[(size_t)ii*HW] = tbuf[pl*TSF + oh*16 + ii];
        }
        __syncthreads();
    }
}

extern "C" void kernel_launch(void* const* d_in, const int* in_sizes, int n_in,
                              void* d_out, int out_size, void* d_ws, size_t ws_size,
                              hipStream_t stream) {
    const float* x    = (const float*)d_in[0];
    const float* wqkv = (const float*)d_in[1];
    const float* bqkv = (const float*)d_in[2];
    const float* wmlp = (const float*)d_in[3];
    float* outp = (float*)d_out;

    short* wsq = (short*)d_ws;                      // 24576 B
    short* wsm = wsq + WSQ_SHORTS;                  // 73728 B  (total 98304 B)

    prep_pack<<<128, 256, 0, stream>>>(wqkv, wmlp, wsq, wsm);

    dim3 grid(WW/TW, HH/TH, 4);
    fused_mfma<<<grid, 256, 0, stream>>>(x, wsq, bqkv, wsm, outp);
}

// Round 2
// 284.112 us; speedup vs baseline: 1.3099x; 1.0914x over previous
//
#include <hip/hip_runtime.h>
#include <hip/hip_bf16.h>

typedef __attribute__((ext_vector_type(8))) short short8;
typedef __attribute__((ext_vector_type(4))) short short4_;
typedef __attribute__((ext_vector_type(4))) float float4_;

#define CH 64
#define HH 256
#define WW 256
#define HW (HH*WW)
#define CHW (CH*HW)

#define TW 16
#define TH 8
#define XPW 20
#define XPH 12
#define NXP 240        // x/qkv halo set (halo 2)
#define OPW 18
#define OPH 10
#define NOP 180        // out1 set (halo 1)

#define XLS 72         // x LDS row stride (shorts) -> 144 B, 16B aligned
#define KQS 20         // k/q chunk row stride (shorts): 10 dwords -> quads hit
                       // disjoint bank octets (8*quad + n16/2): conflict-free stores
#define O1S 72         // out1 row stride (shorts), 144 B = 9*16 -> b128-alignable
#define TSF 33         // tbuf row stride (floats): reads spread all 32 banks

#define KQ_SZ   (NXP*KQS)            // 4800 shorts
#define O1_OFF  KQ_SZ                // o1b shares qbuf region (time-disjoint)
#define SMEM_SHORTS (O1_OFF + NOP*O1S)   // 4800 + 12960 = 17760 -> 35520 B
                                         // (xls needs 17280 <= 17760: ok)

// ws layout: wsq bf16 [0,24576) ; wsm bf16 [24576, 98304)
#define WSQ_SHORTS 12288
#define WSM_SHORTS 36864

__device__ __forceinline__ float b2f(unsigned short u) {
    return __uint_as_float(((unsigned)u) << 16);
}
__device__ __forceinline__ short f2bs(float f) {
    __hip_bfloat16 h = __float2bfloat16(f);
    short s; __builtin_memcpy(&s, &h, 2); return s;
}

// ---- prep: pack wqkv/wmlp to bf16 in exact B-fragment order -----------------
__global__ void prep_pack(const float* __restrict__ wqkv,
                          const float* __restrict__ wmlp,
                          short* __restrict__ wsq, short* __restrict__ wsm) {
    int idx = blockIdx.x * blockDim.x + threadIdx.x;
    int stride = gridDim.x * blockDim.x;
    for (int e = idx; e < WSQ_SHORTS; e += stride) {
        int j = e & 7, lane = (e >> 3) & 63;
        int ks = (e >> 9) & 1, q16 = (e >> 10) & 3, sec = e >> 12;
        int row = sec*64 + q16*16 + (lane & 15);
        int kk  = ks*32 + (lane >> 4)*8 + j;
        wsq[e] = f2bs(wqkv[(size_t)row*64 + kk]);
    }
    for (int e = idx; e < WSM_SHORTS; e += stride) {
        int j = e & 7, lane = (e >> 3) & 63;
        int rest = e >> 9;            // 0..71
        int nt = rest / 18, ks = rest % 18;
        int o   = nt*16 + (lane & 15);
        int cin = (ks & 1)*32 + (lane >> 4)*8 + j;
        int tap = ks >> 1;
        wsm[e] = f2bs(wmlp[(size_t)o*576 + cin*9 + tap]);
    }
}

// ---- fused kernel -----------------------------------------------------------
// LDS 35520 B -> 4 blocks/CU is the LDS-imposed cap; __launch_bounds__ stays
// at (256,3): round-1 evidence showed (256,4) pinned the allocator at the
// 64-VGPR step and spilled resi/afr to scratch (+250 MB HBM traffic,
// VGPR 84->64). With ~170-reg budget the natural ~84-reg allocation gives
// 4 blocks/CU at runtime anyway (min of LDS cap and VGPR step 65-128).
__global__ __launch_bounds__(256, 3) void fused_mfma(
    const float* __restrict__ x, const short* __restrict__ wsq,
    const float* __restrict__ bqkv, const short* __restrict__ wsm,
    float* __restrict__ out)
{
    __shared__ __align__(16) short smem[SMEM_SHORTS];
    short* xls  = smem;                              // [240][72] (phase X only)
    short* kbuf = smem;                              // [240][20]
    short* qbuf = smem + O1_OFF;                     // [240][20] (QK rounds)
    short* o1b  = smem + O1_OFF;                     // [180][72] (V rounds/conv)
    float* tbuf = (float*)smem;                      // [128][33] (conv epilogue)

    const int t    = threadIdx.x;
    const int w    = t >> 6;
    const int lane = t & 63;
    const int n16  = lane & 15;
    const int quad = lane >> 4;

    // XCD-chunk swizzle: HW round-robins consecutive linear block ids across
    // the 8 XCDs. Remap so XCD k owns a CONTIGUOUS half-image (256 tiles):
    // adjacent tiles (bx+-1, by+-1) then share one L2 -> x-halo reads hit L2
    // and the two 64B halves of each 128B out line (written by bx, bx+1)
    // merge before writeback instead of double RMW across XCDs.
    // 2048 % 8 == 0 -> bijective.
    const int d  = blockIdx.x + (blockIdx.y << 4) + (blockIdx.z << 9);
    const int n  = ((d & 7) << 8) | (d >> 3);
    const int b   = n >> 9;
    const int rem = n & 511;
    const int gy0 = (rem >> 4) * TH;
    const int gx0 = (rem & 15) * TW;
    const float* xb = x + (size_t)b * CHW;

    // NOTE: all 4 waves process exactly 4 M-tiles (16th tile is a clamped
    // dummy) so that every register-array index is compile-time static.
    // Dynamic-bound loops over register arrays (round 5/6) caused scratch
    // spills: WRITE_SIZE 188MB vs 67MB ideal.

    // ---- phase X: stage x halo tile into LDS bf16, coalesced float4 loads
    for (int slot = t; slot < 64*12*6; slot += 256) {
        int s6 = slot % 6, y = (slot / 6) % 12, c = slot / 72;
        int gy = gy0 - 2 + y;
        int gxb = gx0 - 4 + s6*4;
        float v[4];
        bool gyok = (unsigned)gy < HH;
        if (gyok && gxb >= 0 && gxb + 3 < WW) {
            float4_ f4 = *(const float4_*)(xb + (size_t)c*HW + gy*WW + gxb);
            v[0]=f4[0]; v[1]=f4[1]; v[2]=f4[2]; v[3]=f4[3];
        } else {
            #pragma unroll
            for (int i = 0; i < 4; ++i) {
                int gx = gxb + i;
                v[i] = (gyok && (unsigned)gx < WW) ? xb[(size_t)c*HW + gy*WW + gx] : 0.f;
            }
        }
        #pragma unroll
        for (int i = 0; i < 4; ++i) {
            int pxc = s6*4 + i - 2;
            if ((unsigned)pxc < XPW)
                xls[(y*XPW + pxc)*XLS + c] = f2bs(v[i]);
        }
    }
    __syncthreads();

    // OOB bitmask: bit(i*4+r) -> halo pixel (w*4+i)*16 + quad*4 + r
    unsigned okbits = 0;
    #pragma unroll
    for (int i = 0; i < 4; ++i)
        #pragma unroll
        for (int r = 0; r < 4; ++r) {
            int p = (w*4 + i)*16 + quad*4 + r;
            if (p < NXP) {
                int gy = gy0 - 2 + p / XPW, gx = gx0 - 2 + p % XPW;
                if (((unsigned)gy < HH) && ((unsigned)gx < WW))
                    okbits |= 1u << (i*4 + r);
            }
        }

    // ---- A-frags (from LDS, static-indexed) + residual capture
    short8 afr[4][2];
    #pragma unroll
    for (int i = 0; i < 4; ++i) {
        int p = (w*4 + i)*16 + n16;
        int pr = (p < NXP) ? p : 0;        // clamped dummy for wave3/i3
        #pragma unroll
        for (int ks = 0; ks < 2; ++ks)
            afr[i][ks] = *(const short8*)&xls[pr*XLS + ks*32 + quad*8];
    }
    // per-thread attention pixel
    const int op_py = t / OPW, op_px = t % OPW;
    const int ogy = gy0 - 1 + op_py, ogx = gx0 - 1 + op_px;
    const bool oin = (t < NOP) && ((unsigned)ogy < HH) && ((unsigned)ogx < WW);
    const int xpix = (op_py + 1)*XPW + (op_px + 1);
    short8 resi[8];
    if (t < NOP) {
        #pragma unroll
        for (int g = 0; g < 8; ++g)
            resi[g] = *(const short8*)&xls[xpix*XLS + g*8];
    }
    __syncthreads();   // xls dead; k/q regions may now be written

    // gemm one 16-outch chunk of section sec (0=q,1=k,2=v) into dst
    auto gemm16 = [&](int sec, int q16, short* dst) {
        short8 b0 = *(const short8*)&wsq[(((sec*4 + q16)*2 + 0) << 9) + lane*8];
        short8 b1 = *(const short8*)&wsq[(((sec*4 + q16)*2 + 1) << 9) + lane*8];
        float bias = bqkv[sec*64 + q16*16 + n16];
        #pragma unroll
        for (int i = 0; i < 4; ++i) {
            float4_ c = {0.f, 0.f, 0.f, 0.f};
            c = __builtin_amdgcn_mfma_f32_16x16x32_bf16(afr[i][0], b0, c, 0, 0, 0);
            c = __builtin_amdgcn_mfma_f32_16x16x32_bf16(afr[i][1], b1, c, 0, 0, 0);
            #pragma unroll
            for (int r = 0; r < 4; ++r) {
                int p = (w*4 + i)*16 + quad*4 + r;
                bool ok = (okbits >> (i*4 + r)) & 1u;
                if (p < NXP)                        // guard dummy tile
                    dst[p*KQS + n16] = ok ? f2bs(c[r] + bias) : (short)0;
            }
        }
    };

    // ---- QK rounds (4 x 16 channels) + dot accumulation
    float dots[9];
    #pragma unroll
    for (int n2 = 0; n2 < 9; ++n2) dots[n2] = 0.f;

    #pragma unroll
    for (int q16 = 0; q16 < 4; ++q16) {
        gemm16(0, q16, qbuf);
        gemm16(1, q16, kbuf);
        __syncthreads();
        if (oin) {
            #pragma unroll
            for (int g = 0; g < 4; ++g) {
                short4_ q4 = *(const short4_*)&qbuf[xpix*KQS + g*4];
                float qv[4];
                #pragma unroll
                for (int j = 0; j < 4; ++j) qv[j] = b2f((unsigned short)q4[j]);
                #pragma unroll
                for (int n2 = 0; n2 < 9; ++n2) {
                    int np = xpix + (n2/3 - 1)*XPW + (n2%3 - 1);
                    short4_ k4 = *(const short4_*)&kbuf[np*KQS + g*4];
                    #pragma unroll
                    for (int j = 0; j < 4; ++j) dots[n2] += qv[j] * b2f((unsigned short)k4[j]);
                }
            }
        }
        __syncthreads();
    }

    // ---- softmax (registers)
    float attn[9];
    if (oin) {
        float mx = -1e30f;
        #pragma unroll
        for (int n2 = 0; n2 < 9; ++n2) { dots[n2] *= 0.125f; mx = fmaxf(mx, dots[n2]); }
        float se = 0.f;
        #pragma unroll
        for (int n2 = 0; n2 < 9; ++n2) { attn[n2] = __expf(dots[n2] - mx); se += attn[n2]; }
        float inv = 1.f / se;
        #pragma unroll
        for (int n2 = 0; n2 < 9; ++n2) attn[n2] *= inv;
    }

    // ---- V rounds (4 x 16 channels): gemm v -> aggregate into o1b (bf16)
    // o1b writes are two ds_write_b128 per thread (16B-aligned rows; per-bank
    // load is uniform 8 accesses = the b128 minimum -> no extra serialization)
    #pragma unroll
    for (int q16 = 0; q16 < 4; ++q16) {
        gemm16(2, q16, kbuf);
        __syncthreads();
        if (t < NOP) {
            short8 s0, s1;
            if (oin) {
                float o1[16];
                #pragma unroll
                for (int h = 0; h < 2; ++h) {
                    short8 rg = resi[q16*2 + h];
                    #pragma unroll
                    for (int j = 0; j < 8; ++j) o1[h*8 + j] = b2f((unsigned short)rg[j]);
                }
                #pragma unroll
                for (int n2 = 0; n2 < 9; ++n2) {
                    float a = attn[n2];
                    int np = xpix + (n2/3 - 1)*XPW + (n2%3 - 1);
                    #pragma unroll
                    for (int g = 0; g < 4; ++g) {
                        short4_ v4 = *(const short4_*)&kbuf[np*KQS + g*4];
                        #pragma unroll
                        for (int j = 0; j < 4; ++j) o1[g*4 + j] += a * b2f((unsigned short)v4[j]);
                    }
                }
                #pragma unroll
                for (int j = 0; j < 8; ++j) {
                    s0[j] = f2bs(o1[j]);
                    s1[j] = f2bs(o1[8 + j]);
                }
            } else {
                #pragma unroll
                for (int j = 0; j < 8; ++j) { s0[j] = 0; s1[j] = 0; }  // conv zero-pad
            }
            *(short8*)&o1b[t*O1S + q16*16]     = s0;
            *(short8*)&o1b[t*O1S + q16*16 + 8] = s1;
        }
        __syncthreads();
    }

    // ---- 3x3 conv 64->64 as one MFMA burst (K=576 tap-major), B from ws
    float4_ acc[4][2];
    #pragma unroll
    for (int nt = 0; nt < 4; ++nt) {
        acc[nt][0] = (float4_){0.f,0.f,0.f,0.f};
        acc[nt][1] = (float4_){0.f,0.f,0.f,0.f};
    }
    const int mtc0 = w*2, mtc1 = w*2 + 1;
    for (int ks = 0; ks < 18; ++ks) {
        int tap = ks >> 1;
        int dy = tap/3 - 1, dx = tap%3 - 1;
        int cin0 = (ks & 1)*32 + quad*8;
        int pixA = (mtc0 + 1 + dy)*OPW + (n16 + 1 + dx);
        int pixB = (mtc1 + 1 + dy)*OPW + (n16 + 1 + dx);
        short8 a0 = *(const short8*)&o1b[pixA*O1S + cin0];
        short8 a1 = *(const short8*)&o1b[pixB*O1S + cin0];
        #pragma unroll
        for (int nt = 0; nt < 4; ++nt) {
            short8 bb = *(const short8*)&wsm[((nt*18 + ks) << 9) + lane*8];
            acc[nt][0] = __builtin_amdgcn_mfma_f32_16x16x32_bf16(a0, bb, acc[nt][0], 0, 0, 0);
            acc[nt][1] = __builtin_amdgcn_mfma_f32_16x16x32_bf16(a1, bb, acc[nt][1], 0, 0, 0);
        }
    }
    __syncthreads();   // o1b overlaps tbuf region now: all conv reads must land

    // ---- epilogue: two 32-channel halves through tbuf, coalesced stores
    #pragma unroll
    for (int half = 0; half < 2; ++half) {
        #pragma unroll
        for (int ntl = 0; ntl < 2; ++ntl) {
            int nt = half*2 + ntl;
            #pragma unroll
            for (int r = 0; r < 4; ++r) {
                tbuf[(mtc0*16 + quad*4 + r)*TSF + ntl*16 + n16] = fmaxf(acc[nt][0][r], 0.f);
                tbuf[(mtc1*16 + quad*4 + r)*TSF + ntl*16 + n16] = fmaxf(acc[nt][1][r], 0.f);
            }
        }
        __syncthreads();
        {
            int pl = t & 127, oh = t >> 7;
            int ty_ = pl >> 4, tx_ = pl & 15;
            float* op = out + (size_t)b*CHW + (size_t)(half*32 + oh*16)*HW
                        + (size_t)(gy0 + ty_)*WW + (gx0 + tx_);
            #pragma unroll
            for (int ii = 0; ii < 16; ++ii)
                op[(size_t)ii*HW] = tbuf[pl*TSF + oh*16 + ii];
        }
        __syncthreads();
    }
}

extern "C" void kernel_launch(void* const* d_in, const int* in_sizes, int n_in,
                              void* d_out, int out_size, void* d_ws, size_t ws_size,
                              hipStream_t stream) {
    const float* x    = (const float*)d_in[0];
    const float* wqkv = (const float*)d_in[1];
    const float* bqkv = (const float*)d_in[2];
    const float* wmlp = (const float*)d_in[3];
    float* outp = (float*)d_out;

    short* wsq = (short*)d_ws;                      // 24576 B
    short* wsm = wsq + WSQ_SHORTS;                  // 73728 B  (total 98304 B)

    prep_pack<<<128, 256, 0, stream>>>(wqkv, wmlp, wsq, wsm);

    dim3 grid(WW/TW, HH/TH, 4);
    fused_mfma<<<grid, 256, 0, stream>>>(x, wsq, bqkv, wsm, outp);
}